// Round 11
// baseline (3458.473 us; speedup 1.0000x reference)
//
#include <hip/hip_runtime.h>
#include <hip/hip_bf16.h>

#define SEQ_   128
#define NCLS_  50257
#define EMB_   1024
#define HID_   1024
#define BATCH_ 1024
#define G4_    4096

typedef __attribute__((ext_vector_type(8))) short short8;
typedef __attribute__((ext_vector_type(4))) float f32x4;

__device__ __forceinline__ void async_copy16(void* lds, const void* g) {
  __builtin_amdgcn_global_load_lds(
      (const __attribute__((address_space(1))) void*)g,
      (__attribute__((address_space(3))) void*)lds, 16, 0, 0);
}

__device__ __forceinline__ void mfma_acc(f32x4& c, const short8& a, const short8& b) {
  asm("v_mfma_f32_16x16x32_bf16 %0, %1, %2, %0" : "+v"(c) : "v"(a), "v"(b));
}

__device__ __forceinline__ float sigmoidf_(float x) {
  return 1.f / (1.f + __expf(-x));
}
__device__ __forceinline__ float tanhf_(float x) {
  x = fminf(12.f, fmaxf(-12.f, x));
  float e = __expf(2.f * x);
  return (e - 1.f) / (e + 1.f);
}
__device__ __forceinline__ float bf2f_(ushort u) {
  return __uint_as_float(((unsigned int)u) << 16);
}

// ---------------------------------------------------------------------------
// gemm256: C[M,N] = A[M,1024] x B[1024,N].  A bf16 k-swizzled rows, staged
// into a TRIPLE-buffered 48 KB LDS (one 128x64 tile per slot). B is read
// directly to registers from a fragment-packed layout (r7 pack scheme) —
// no B LDS, no B barrier dependency. 512 thr = 8 waves (wm 0..1 x wn 0..3),
// per-wave output 64 rows x 64 cols, acc[4][4]. ONE barrier per K-tile,
// counted vmcnt(2) derived from issue order:
//   [top]  LOADB(kc+1)[8]  STAGE(kc+2)[2]
//   [end]  vmcnt(2) -> completes STAGE(kc+1)+LOADB(kc+1), leaves STAGE(kc+2)
// EPI 0 (E_proj): outB = bf16(acc + bias0[col]); grid: xcd-pinned tx pairs.
// EPI 2 (logits): outF = acc + bias0[col], col<Nreal; grid: tx-major.
// ---------------------------------------------------------------------------
template <int EPI>
__global__ __launch_bounds__(512) void gemm256(
    const __hip_bfloat16* __restrict__ A,     // [M][1024] k-swizzled
    const __hip_bfloat16* __restrict__ Bpk,   // fragment-packed B
    float* __restrict__ outF, __hip_bfloat16* __restrict__ outB,
    int Mreal, int Nreal, long ostride, const float* __restrict__ bias0) {
  __shared__ __align__(16) __hip_bfloat16 lA[3 * 128 * 64];  // 48 KB

  const int tid = threadIdx.x;
  const int lane = tid & 63;
  const int w = tid >> 6;
  const int wm = w >> 2;   // 0..1 (64-row half)
  const int wn = w & 3;    // 0..3 (64-col quarter)

  int tx, ty;
  if constexpr (EPI == 0) {   // E_proj: 16 tx, 394 ty; tx pair pinned per XCD
    const int om = blockIdx.x & 7;
    const int idx = blockIdx.x >> 3;
    tx = om * 2 + (idx & 1);
    ty = idx >> 1;
  } else {                    // logits: 197 tx, 8 ty; x-tile's 8 y co-dispatch
    tx = blockIdx.x >> 3;
    ty = blockIdx.x & 7;
  }
  const int m0 = ty * 128;
  const int n0 = tx * 256;

  const int fr = lane & 15;
  const int kb = (lane >> 4) * 16;
  const int swz = (fr & 7) << 4;

  // per-wave packed-B base: frag(nf,kc,kk) = bb + (nf*32 + kc*2 + kk)*512
  const __hip_bfloat16* bb = Bpk + (size_t)(tx * 4 + wn) * 128 * 512 + lane * 8;

  f32x4 acc[4][4];
#pragma unroll
  for (int i = 0; i < 4; ++i)
#pragma unroll
    for (int j = 0; j < 4; ++j) acc[i][j] = (f32x4)(0.0f);

  auto STAGE = [&](int kc, int slot) {
#pragma unroll
    for (int q = 0; q < 2; ++q) {
      const int r = q * 512 + tid;       // 0..1023 16B-chunks
      const int row = r >> 3, ch = r & 7;
      long ar = m0 + row;
      if (EPI == 0 && ar >= Mreal) ar = Mreal - 1;  // discarded rows
      async_copy16((char*)lA + slot * 16384 + r * 16,
                   (const char*)(A + ar * 1024 + kc * 64 + ch * 8));
    }
  };

  short8 bR[2][2][4];  // [kc&1][kk][nf]
  auto LOADB = [&](int kc) {
#pragma unroll
    for (int kk = 0; kk < 2; ++kk)
#pragma unroll
      for (int nf = 0; nf < 4; ++nf)
        bR[kc & 1][kk][nf] =
            *(const short8*)(bb + (nf * 32 + kc * 2 + kk) * 512);
  };

  // prologue: bR0 first (vmcnt accounting), then A0, A1
  LOADB(0);
  __builtin_amdgcn_sched_barrier(0);
  STAGE(0, 0);
  STAGE(1, 1);
  __builtin_amdgcn_sched_barrier(0);
  asm volatile("s_waitcnt vmcnt(2)" ::: "memory");  // bR0 + A0 done; A1 flying
  __builtin_amdgcn_s_barrier();

#pragma unroll 2
  for (int kc = 0; kc < 16; ++kc) {
    if (kc < 15) LOADB(kc + 1);
    __builtin_amdgcn_sched_barrier(0);
    if (kc < 14) STAGE(kc + 2, (kc + 2) % 3);
    __builtin_amdgcn_sched_barrier(0);

    const char* baseA = (const char*)lA + (kc % 3) * 16384;
    short8 aR[4];
#pragma unroll
    for (int f = 0; f < 4; ++f)
      aR[f] = *(const short8*)(baseA + (wm * 64 + f * 16 + fr) * 128 +
                               (kb ^ swz));
    __builtin_amdgcn_s_setprio(1);
#pragma unroll
    for (int fm = 0; fm < 4; ++fm)
#pragma unroll
      for (int nf = 0; nf < 4; ++nf)
        mfma_acc(acc[fm][nf], aR[fm], bR[kc & 1][0][nf]);
    __builtin_amdgcn_s_setprio(0);
#pragma unroll
    for (int f = 0; f < 4; ++f)
      aR[f] = *(const short8*)(baseA + (wm * 64 + f * 16 + fr) * 128 +
                               ((64 + kb) ^ swz));
    __builtin_amdgcn_s_setprio(1);
#pragma unroll
    for (int fm = 0; fm < 4; ++fm)
#pragma unroll
      for (int nf = 0; nf < 4; ++nf)
        mfma_acc(acc[fm][nf], aR[fm], bR[kc & 1][1][nf]);
    __builtin_amdgcn_s_setprio(0);
    __builtin_amdgcn_sched_barrier(0);

    if (kc < 14)       asm volatile("s_waitcnt vmcnt(2)" ::: "memory");
    else if (kc == 14) asm volatile("s_waitcnt vmcnt(0)" ::: "memory");
    if (kc < 15) __builtin_amdgcn_s_barrier();
  }

  // epilogue
  const int cn = lane & 15;
  const int rb = (lane >> 4) * 4;
#pragma unroll
  for (int nf = 0; nf < 4; ++nf) {
    const int col = n0 + wn * 64 + nf * 16 + cn;
    const float badd = (EPI == 0) ? bias0[col]
                                  : ((col < Nreal) ? bias0[col] : 0.f);
#pragma unroll
    for (int fm = 0; fm < 4; ++fm) {
#pragma unroll
      for (int r = 0; r < 4; ++r) {
        const int row = m0 + wm * 64 + fm * 16 + rb + r;
        const float v = acc[fm][nf][r] + badd;
        if (EPI == 0) {
          if (row < Mreal) outB[(long)row * ostride + col] = __float2bfloat16(v);
        } else {
          if (col < Nreal) outF[(long)row * ostride + col] = v;
        }
      }
    }
  }
}

// ---------------------------------------------------------------------------
// Fragment packs. Layout (all): tile = ((tx*4+wn)*4+nf)*32 + kc*2 + kk,
// 1 KB/tile; lane l holds col (l&15), k-slot (l>>4): k = kc*64+kk*32+(l>>4)*8+e.
// ---------------------------------------------------------------------------
// Wx [1024][4096] fp32, gate-interleaved cols: n=4h+g -> src col g*1024+h.
__global__ __launch_bounds__(256) void pack_wx(const float* __restrict__ Wx,
                                               __hip_bfloat16* __restrict__ Bpk) {
  const int gtid = blockIdx.x * 256 + threadIdx.x;  // 0..524287
  const int l = gtid & 63;
  const int tile = gtid >> 6;      // 0..8191
  const int kk = tile & 1;
  const int kc = (tile >> 1) & 15;
  const int nf = (tile >> 5) & 3;
  const int wn = (tile >> 7) & 3;
  const int tx = tile >> 9;        // 0..15
  const int n = tx * 256 + wn * 64 + nf * 16 + (l & 15);
  const int g = n & 3, h = n >> 2;
  const int k0 = kc * 64 + kk * 32 + (l >> 4) * 8;
  short8 v;
#pragma unroll
  for (int e = 0; e < 8; ++e) {
    const __hip_bfloat16 b =
        __float2bfloat16(Wx[(size_t)(k0 + e) * G4_ + g * 1024 + h]);
    v[e] = *reinterpret_cast<const short*>(&b);
  }
  *(short8*)(Bpk + (size_t)gtid * 8) = v;
}

// Wo [1024][50257] fp32, plain cols, zero-pad n >= NCLS. tx 0..196.
__global__ __launch_bounds__(256) void pack_wo(const float* __restrict__ Wo,
                                               __hip_bfloat16* __restrict__ Bpk) {
  const int gtid = blockIdx.x * 256 + threadIdx.x;  // 0..6455295
  const int l = gtid & 63;
  const int tile = gtid >> 6;      // 0..100863
  const int kk = tile & 1;
  const int kc = (tile >> 1) & 15;
  const int nf = (tile >> 5) & 3;
  const int wn = (tile >> 7) & 3;
  const int tx = tile >> 9;        // 0..196
  const int n = tx * 256 + wn * 64 + nf * 16 + (l & 15);
  const int k0 = kc * 64 + kk * 32 + (l >> 4) * 8;
  short8 v;
#pragma unroll
  for (int e = 0; e < 8; ++e) {
    float f = (n < NCLS_) ? Wo[(size_t)(k0 + e) * NCLS_ + n] : 0.f;
    const __hip_bfloat16 b = __float2bfloat16(f);
    v[e] = *reinterpret_cast<const short*>(&b);
  }
  *(short8*)(Bpk + (size_t)gtid * 8) = v;
}

// Wh pack (r7 layout, proven): tile = ((ht*2+wn)*2+kh)*64 + kc*8 + kk*4 + g.
__global__ __launch_bounds__(256) void pack_b(const float* __restrict__ Wh,
                                              __hip_bfloat16* __restrict__ Bpk) {
  const int gtid = blockIdx.x * 256 + threadIdx.x;  // 0..524287
  const int l = gtid & 63;
  const int tile = gtid >> 6;                       // 0..8191
  const int g = tile & 3;
  const int kk = (tile >> 2) & 1;
  const int kc = (tile >> 3) & 7;
  const int kh = (tile >> 6) & 1;
  const int wn = (tile >> 7) & 1;
  const int ht = tile >> 8;
  const int h = ht * 32 + wn * 16 + (l & 15);
  const int k0 = kh * 512 + kc * 64 + kk * 32 + (l >> 4) * 8;
  short8 v;
#pragma unroll
  for (int e = 0; e < 8; ++e) {
    const __hip_bfloat16 b = __float2bfloat16(Wh[(size_t)(k0 + e) * G4_ + g * 1024 + h]);
    v[e] = *reinterpret_cast<const short*>(&b);
  }
  *(short8*)(Bpk + (size_t)gtid * 8) = v;
}

// ---------------------------------------------------------------------------
// Fused LSTM step (r7 version — best measured). Grid 256, 512 threads,
// 96 KB dynamic LDS (3 x 32KB A bufs), B direct-to-register from Bpk.
// ---------------------------------------------------------------------------
__global__ __launch_bounds__(512, 2) void lstm_step(
    const __hip_bfloat16* __restrict__ hprev,   // [1024][1024] swizzled
    const __hip_bfloat16* __restrict__ Bpk,     // packed Wh (8 MB)
    const __hip_bfloat16* __restrict__ Epr,     // [V][4096] col=4h+g
    const int* __restrict__ X,
    float* __restrict__ cbuf,                   // [1024][1024] f32
    __hip_bfloat16* __restrict__ hnext,         // swizzled
    __hip_bfloat16* __restrict__ hfin,          // swizzled (last step)
    int t, int last) {
  extern __shared__ __align__(16) char smem[];  // 98304 = 3 x 32KB A bufs
  float* gacc = (float*)smem;                   // [128][132] f32 (aliases)

  const int tid = threadIdx.x;
  const int lane = tid & 63;
  const int w = tid >> 6;
  const int wm = (w >> 1) & 1;
  const int wn = w & 1;
  const int kh = w >> 2;
  const int bid = blockIdx.x;
  const int xcd = bid & 7;
  const int j = bid >> 3;
  const int ht = xcd * 4 + (j & 3);   // Bpk slice pinned to one XCD's L2
  const int mt = j >> 2;
  const int m0 = mt * 128;
  const int h0 = ht * 32;

  const int fr = lane & 15;
  const int kb = (lane >> 4) * 16;
  const int swz = (fr & 7) << 4;
  const int cn = lane & 15;
  const int rb = (lane >> 4) * 4;

  const int crow = tid >> 2;
  const int hq = tid & 3;
  const int prow = m0 + crow;
  const int tok1 = X[prow * SEQ_ + t];

  const __hip_bfloat16* bb =
      Bpk + (size_t)(((ht * 2 + wn) * 2 + kh) * 64) * 512 + lane * 8;

  f32x4 acc[4][4];  // [fm][gate]
#pragma unroll
  for (int i = 0; i < 4; ++i)
#pragma unroll
    for (int g = 0; g < 4; ++g) acc[i][g] = (f32x4)(0.0f);

  auto STAGE_A = [&](int kc, int b) {
#pragma unroll
    for (int q = 0; q < 4; ++q) {
      const int region = q >> 1;           // kh-half
      const int r = (q & 1) * 512 + tid;   // 0..1023 chunks
      const int row = r >> 3, ch = r & 7;
      const __hip_bfloat16* src =
          hprev + (size_t)(m0 + row) * HID_ + region * 512 + kc * 64 + ch * 8;
      async_copy16(smem + b * 32768 + region * 16384 + r * 16, src);
    }
  };

  short8 bR[2][2][4];  // [kc&1][kk][g]

  STAGE_A(0, 0);
#pragma unroll
  for (int kk = 0; kk < 2; ++kk)
#pragma unroll
    for (int g = 0; g < 4; ++g)
      bR[0][kk][g] = *(const short8*)(bb + (0 * 8 + kk * 4 + g) * 512);
  STAGE_A(1, 1);

#pragma unroll
  for (int kc = 0; kc < 8; ++kc) {
    __builtin_amdgcn_s_barrier();
    if (kc + 1 < 8) {
#pragma unroll
      for (int kk = 0; kk < 2; ++kk)
#pragma unroll
        for (int g = 0; g < 4; ++g)
          bR[(kc + 1) & 1][kk][g] =
              *(const short8*)(bb + ((kc + 1) * 8 + kk * 4 + g) * 512);
    }
    if (kc + 2 < 8) STAGE_A(kc + 2, (kc + 2) % 3);
    if (kc < 6)      asm volatile("s_waitcnt vmcnt(24)" ::: "memory");
    else if (kc == 6) asm volatile("s_waitcnt vmcnt(20)" ::: "memory");
    else             asm volatile("s_waitcnt vmcnt(8)" ::: "memory");
    __builtin_amdgcn_sched_barrier(0);

    const char* baseA = smem + (kc % 3) * 32768 + kh * 16384;
    short8 aR[2][4];
#pragma unroll
    for (int kk = 0; kk < 2; ++kk)
#pragma unroll
      for (int f = 0; f < 4; ++f)
        aR[kk][f] = *(const short8*)(baseA + (wm * 64 + f * 16 + fr) * 128 +
                                     ((kk * 64 + kb) ^ swz));
    __builtin_amdgcn_s_setprio(1);
#pragma unroll
    for (int fm = 0; fm < 4; ++fm)
#pragma unroll
      for (int g = 0; g < 4; ++g) {
        mfma_acc(acc[fm][g], aR[0][fm], bR[kc & 1][0][g]);
        mfma_acc(acc[fm][g], aR[1][fm], bR[kc & 1][1][g]);
      }
    __builtin_amdgcn_s_setprio(0);
  }

  ushort4 ep[8];
  float cold[8];
#pragma unroll
  for (int jj = 0; jj < 8; ++jj) {
    ep[jj] = *(const ushort4*)(Epr + (size_t)tok1 * G4_ + (h0 + hq * 8 + jj) * 4);
    cold[jj] = cbuf[(size_t)prow * HID_ + h0 + hq * 8 + jj];
  }

  __syncthreads();
  if (kh == 0) {
#pragma unroll
    for (int fm = 0; fm < 4; ++fm)
#pragma unroll
      for (int g = 0; g < 4; ++g)
#pragma unroll
        for (int r = 0; r < 4; ++r)
          gacc[(wm * 64 + fm * 16 + rb + r) * 132 + (wn * 16 + cn) * 4 + g] =
              acc[fm][g][r];
  }
  __syncthreads();
  if (kh == 1) {
#pragma unroll
    for (int fm = 0; fm < 4; ++fm)
#pragma unroll
      for (int g = 0; g < 4; ++g)
#pragma unroll
        for (int r = 0; r < 4; ++r)
          gacc[(wm * 64 + fm * 16 + rb + r) * 132 + (wn * 16 + cn) * 4 + g] +=
              acc[fm][g][r];
  }
  __syncthreads();

  const float* gr = gacc + crow * 132 + hq * 32;
  f32x4 cnew0, cnew1;
  short8 hv;
#pragma unroll
  for (int jj = 0; jj < 8; ++jj) {
    const f32x4 g4 = *(const f32x4*)(gr + jj * 4);
    const float iv = sigmoidf_(g4[0] + bf2f_(ep[jj].x));
    const float fv = sigmoidf_(g4[1] + bf2f_(ep[jj].y));
    const float gv = tanhf_(g4[2] + bf2f_(ep[jj].z));
    const float ov = sigmoidf_(g4[3] + bf2f_(ep[jj].w));
    const float cv = fv * cold[jj] + iv * gv;
    if (jj < 4) cnew0[jj] = cv; else cnew1[jj - 4] = cv;
    const float hval = ov * tanhf_(cv);
    const __hip_bfloat16 hb = __float2bfloat16(hval);
    hv[jj] = *reinterpret_cast<const short*>(&hb);
  }
  float* cdst = cbuf + (size_t)prow * HID_ + h0 + hq * 8;
  *(f32x4*)cdst = cnew0;
  *(f32x4*)(cdst + 4) = cnew1;
  const int hcolb = h0 + hq * 8;
  const int hswb = (hcolb & ~63) | ((hcolb & 63) ^ ((prow & 7) << 3));
  *(short8*)(hnext + (size_t)prow * HID_ + hswb) = hv;
  if (last) *(short8*)(hfin + (size_t)prow * HID_ + hswb) = hv;
}

// fp32 -> bf16 flat convert; SWZ: k-XOR-swizzle per 64-col group (1024 cols)
template <bool SWZ>
__global__ __launch_bounds__(256) void conv_bf16_k(const float* __restrict__ in,
                                                   __hip_bfloat16* __restrict__ out, int n4) {
  const int i = blockIdx.x * 256 + threadIdx.x;
  if (i >= n4) return;
  const float4 v = ((const float4*)in)[i];
  int o = i * 4;
  if (SWZ) {
    const int row = o >> 10, col = o & 1023;
    const int cs = (col & ~63) | ((col & 63) ^ ((row & 7) << 3));
    o = (o & ~1023) | cs;
  }
  out[o + 0] = __float2bfloat16(v.x);
  out[o + 1] = __float2bfloat16(v.y);
  out[o + 2] = __float2bfloat16(v.z);
  out[o + 3] = __float2bfloat16(v.w);
}

// bP[4h+g] = bx[g*1024+h] + bh[g*1024+h]
__global__ __launch_bounds__(256) void bias_perm(const float* __restrict__ bx,
                                                 const float* __restrict__ bh,
                                                 float* __restrict__ bP) {
  const int n = blockIdx.x * 256 + threadIdx.x;
  if (n >= G4_) return;
  const int h = n >> 2, g = n & 3;
  bP[n] = bx[g * HID_ + h] + bh[g * HID_ + h];
}

extern "C" void kernel_launch(void* const* d_in, const int* in_sizes, int n_in,
                              void* d_out, int out_size, void* d_ws, size_t ws_size,
                              hipStream_t stream) {
  const int* X = (const int*)d_in[0];
  const float* C = (const float*)d_in[1];
  const float* Wx = (const float*)d_in[2];
  const float* bx = (const float*)d_in[3];
  const float* Wh = (const float*)d_in[4];
  const float* bh = (const float*)d_in[5];
  const float* Wo = (const float*)d_in[6];
  const float* bo = (const float*)d_in[7];
  float* out = (float*)d_out;

  char* p = (char*)d_ws;
  const size_t szCb   = (size_t)NCLS_ * EMB_ * 2;     // 102.93 MB
  const size_t szPad  = (size_t)G4_ * EMB_ * 2;       // 8.39 MB spill pad
  const size_t szBpk2 = (size_t)G4_ * HID_ * 2;       // Wx frag pack
  const size_t szBpk  = (size_t)G4_ * HID_ * 2;       // Wh frag pack
  const size_t szEpr  = (size_t)NCLS_ * G4_ * 2;      // 411.7 MB
  const size_t szH    = (size_t)BATCH_ * HID_ * 2;
  const size_t szC    = (size_t)BATCH_ * HID_ * 4;
  const size_t szBp   = (size_t)G4_ * 4;
  if (ws_size < szCb + szPad + szBpk2 + szBpk + szEpr + 3 * szH + szC + szBp)
    return;

  __hip_bfloat16* Cb   = (__hip_bfloat16*)p;          // Wopk aliases Cb+pad
  __hip_bfloat16* Wopk = (__hip_bfloat16*)p; p += szCb + szPad;
  __hip_bfloat16* Bpk2 = (__hip_bfloat16*)p; p += szBpk2;
  __hip_bfloat16* Bpk  = (__hip_bfloat16*)p; p += szBpk;
  __hip_bfloat16* Epr  = (__hip_bfloat16*)p; p += szEpr;
  __hip_bfloat16* hA   = (__hip_bfloat16*)p; p += szH;
  __hip_bfloat16* hB   = (__hip_bfloat16*)p; p += szH;
  __hip_bfloat16* hfin = (__hip_bfloat16*)p; p += szH;
  float* cbuf          = (float*)p;          p += szC;
  float* bP            = (float*)p;          p += szBp;

  // 1. C -> bf16, k-swizzled (A operand of E_proj)
  {
    const int n4 = NCLS_ * EMB_ / 4;
    conv_bf16_k<true><<<(n4 + 255) / 256, 256, 0, stream>>>(C, Cb, n4);
  }
  // 2. fragment-pack Wx (gate-interleaved) and Wh
  pack_wx<<<2048, 256, 0, stream>>>(Wx, Bpk2);
  pack_b<<<2048, 256, 0, stream>>>(Wh, Bpk);
  // 3. permuted bias
  bias_perm<<<G4_ / 256, 256, 0, stream>>>(bx, bh, bP);

  // 4. Epr[V][4096] = C @ Wx + (bx+bh)   (grid 16 tx x 394 ty = 6304)
  gemm256<0><<<dim3(6304), 512, 0, stream>>>(
      Cb, Bpk2, nullptr, Epr, NCLS_, G4_, G4_, bP);

  // 5. fragment-pack Wo into Wopk (aliases Cb — Cb dead after step 4)
  pack_wo<<<25216, 256, 0, stream>>>(Wo, Wopk);

  // 6. zero initial state
  hipMemsetAsync(hA, 0, szH, stream);
  hipMemsetAsync(cbuf, 0, szC, stream);

  // 7. 128 fused LSTM steps (r7 config)
  for (int t = 0; t < SEQ_; ++t) {
    const __hip_bfloat16* hp = (t & 1) ? hB : hA;
    __hip_bfloat16* hn = (t & 1) ? hA : hB;
    lstm_step<<<256, 512, 98304, stream>>>(hp, Bpk, Epr, X, cbuf, hn, hfin, t,
                                           (int)(t == SEQ_ - 1));
  }

  // 8. logits = hfin @ W_out + b_out   (grid 197 tx x 8 ty = 1576)
  gemm256<2><<<dim3(1576), 512, 0, stream>>>(
      hfin, Wopk, out, nullptr, BATCH_, NCLS_, NCLS_, bo);
}

// Round 12
// 3168.307 us; speedup vs baseline: 1.0916x; 1.0916x over previous
//
#include <hip/hip_runtime.h>
#include <hip/hip_bf16.h>

#define SEQ_   128
#define NCLS_  50257
#define EMB_   1024
#define HID_   1024
#define BATCH_ 1024
#define G4_    4096

typedef __attribute__((ext_vector_type(8))) short short8;
typedef __attribute__((ext_vector_type(4))) float f32x4;

__device__ __forceinline__ void async_copy16(void* lds, const void* g) {
  __builtin_amdgcn_global_load_lds(
      (const __attribute__((address_space(1))) void*)g,
      (__attribute__((address_space(3))) void*)lds, 16, 0, 0);
}

__device__ __forceinline__ void mfma_acc(f32x4& c, const short8& a, const short8& b) {
  asm("v_mfma_f32_16x16x32_bf16 %0, %1, %2, %0" : "+v"(c) : "v"(a), "v"(b));
}

__device__ __forceinline__ float sigmoidf_(float x) {
  return 1.f / (1.f + __expf(-x));
}
__device__ __forceinline__ float tanhf_(float x) {
  x = fminf(12.f, fmaxf(-12.f, x));
  float e = __expf(2.f * x);
  return (e - 1.f) / (e + 1.f);
}
__device__ __forceinline__ float bf2f_(ushort u) {
  return __uint_as_float(((unsigned int)u) << 16);
}

// ---------------------------------------------------------------------------
// gemm8p: C[M,N] = A[M,1024] x B[1024,N], A and Bt=[N][1024] both bf16 with
// k-XOR-swizzled rows. BM=128, BN=256, 512 thr = 8 waves (wm 0..1 x wn 0..3),
// wave out 64x64 = acc[4][4]. TRIPLE-buffered LDS slots (48 KB each: A 16K +
// B 32K), prefetch distance 2 (stage t+2 into slot (t+2)%3 while reading t%3
// -> no LDS write/read overlap, ever). 2 phases per K-tile (kk=0,1), each:
// stage-3-instrs || 8 ds_read_b128 || barrier || lgkmcnt(0) || setprio ||
// 16 MFMA || barrier. Tile boundary: vmcnt(6) (= L(t+2) in flight, drains
// L(t+1)); t==14: vmcnt(0); never drains mid-pipe otherwise.
// EPI 0: outB = bf16(acc + bias0[col]) ; EPI 2: outF = acc + bias0[col]
// ---------------------------------------------------------------------------
template <int EPI>
__global__ __launch_bounds__(512) void gemm8p(
    const __hip_bfloat16* __restrict__ A,   // [M][1024] k-swizzled
    const __hip_bfloat16* __restrict__ Bt,  // [N][1024] k-swizzled
    float* __restrict__ outF, __hip_bfloat16* __restrict__ outB,
    int Mreal, int Nreal, long ostride, const float* __restrict__ bias0) {
  extern __shared__ __align__(16) char smem[];  // 3 x 49152

  const int tid = threadIdx.x;
  const int lane = tid & 63;
  const int w = tid >> 6;
  const int wm = w >> 2;   // 0..1
  const int wn = w & 3;    // 0..3
  const int m0 = blockIdx.y * 128;
  const int n0 = blockIdx.x * 256;

  const int fr = lane & 15;
  const int kb = (lane >> 4) * 16;
  const int swz = (fr & 7) << 4;

  f32x4 acc[4][4];
#pragma unroll
  for (int i = 0; i < 4; ++i)
#pragma unroll
    for (int j = 0; j < 4; ++j) acc[i][j] = (f32x4)(0.0f);

  // part 0: {A chunk0, A chunk1, B chunk0}; part 1: {B chunk1..3}
  auto STAGE3 = [&](int kc, int part) {
    const int slot = kc % 3;
#pragma unroll
    for (int q = 0; q < 3; ++q) {
      const int inst = part * 3 + q;  // 0..5
      char* dst;
      const __hip_bfloat16* src;
      if (inst < 2) {
        const int r = inst * 512 + tid;  // 0..1023
        const int row = r >> 3, ch = r & 7;
        long ar = m0 + row; if (ar >= Mreal) ar = Mreal - 1;
        src = A + ar * 1024 + kc * 64 + ch * 8;
        dst = smem + slot * 49152 + r * 16;
      } else {
        const int r = (inst - 2) * 512 + tid;  // 0..2047
        const int row = r >> 3, ch = r & 7;
        long br = n0 + row; if (br >= Nreal) br = Nreal - 1;
        src = Bt + br * 1024 + kc * 64 + ch * 8;
        dst = smem + slot * 49152 + 16384 + r * 16;
      }
      async_copy16(dst, src);
    }
  };

  // prologue: L(0)[6], L(1)[6] in flight; vmcnt(6) -> L(0) landed.
  STAGE3(0, 0); STAGE3(0, 1);
  STAGE3(1, 0); STAGE3(1, 1);
  asm volatile("s_waitcnt vmcnt(6)" ::: "memory");
  __builtin_amdgcn_s_barrier();

  for (int t = 0; t < 16; ++t) {
    const char* baseA = smem + (t % 3) * 49152;
    const char* baseB = baseA + 16384;
#pragma unroll
    for (int kk = 0; kk < 2; ++kk) {
      if (t + 2 < 16) STAGE3(t + 2, kk);
      __builtin_amdgcn_sched_barrier(0);

      short8 aR[4], bR[4];
#pragma unroll
      for (int f = 0; f < 4; ++f) {
        aR[f] = *(const short8*)(baseA + (wm * 64 + f * 16 + fr) * 128 +
                                 ((kk * 64 + kb) ^ swz));
        bR[f] = *(const short8*)(baseB + (wn * 64 + f * 16 + fr) * 128 +
                                 ((kk * 64 + kb) ^ swz));
      }
      __builtin_amdgcn_s_barrier();
      asm volatile("s_waitcnt lgkmcnt(0)" ::: "memory");
      __builtin_amdgcn_sched_barrier(0);
      __builtin_amdgcn_s_setprio(1);
#pragma unroll
      for (int fm = 0; fm < 4; ++fm)
#pragma unroll
        for (int fn = 0; fn < 4; ++fn)
          mfma_acc(acc[fm][fn], aR[fm], bR[fn]);
      __builtin_amdgcn_s_setprio(0);
      __builtin_amdgcn_sched_barrier(0);
      if (kk == 1) {
        if (t < 14)       asm volatile("s_waitcnt vmcnt(6)" ::: "memory");
        else if (t == 14) asm volatile("s_waitcnt vmcnt(0)" ::: "memory");
      }
      __builtin_amdgcn_s_barrier();
    }
  }

  const int cn = lane & 15;
  const int rb = (lane >> 4) * 4;
#pragma unroll
  for (int fn = 0; fn < 4; ++fn) {
    const int col = n0 + wn * 64 + fn * 16 + cn;
    const float badd = (EPI == 0) ? bias0[col]
                                  : ((col < Nreal) ? bias0[col] : 0.f);
#pragma unroll
    for (int fm = 0; fm < 4; ++fm) {
#pragma unroll
      for (int r = 0; r < 4; ++r) {
        const int row = m0 + wm * 64 + fm * 16 + rb + r;
        const float v = acc[fm][fn][r] + badd;
        if (EPI == 0) {
          if (row < Mreal) outB[(long)row * ostride + col] = __float2bfloat16(v);
        } else {
          if (col < Nreal) outF[(long)row * ostride + col] = v;
        }
      }
    }
  }
}

// ---------------------------------------------------------------------------
// Wh pack (r7 layout, proven): tile = ((ht*2+wn)*2+kh)*64 + kc*8 + kk*4 + g.
// ---------------------------------------------------------------------------
__global__ __launch_bounds__(256) void pack_b(const float* __restrict__ Wh,
                                              __hip_bfloat16* __restrict__ Bpk) {
  const int gtid = blockIdx.x * 256 + threadIdx.x;  // 0..524287
  const int l = gtid & 63;
  const int tile = gtid >> 6;                       // 0..8191
  const int g = tile & 3;
  const int kk = (tile >> 2) & 1;
  const int kc = (tile >> 3) & 7;
  const int kh = (tile >> 6) & 1;
  const int wn = (tile >> 7) & 1;
  const int ht = tile >> 8;
  const int h = ht * 32 + wn * 16 + (l & 15);
  const int k0 = kh * 512 + kc * 64 + kk * 32 + (l >> 4) * 8;
  short8 v;
#pragma unroll
  for (int e = 0; e < 8; ++e) {
    const __hip_bfloat16 b = __float2bfloat16(Wh[(size_t)(k0 + e) * G4_ + g * 1024 + h]);
    v[e] = *reinterpret_cast<const short*>(&b);
  }
  *(short8*)(Bpk + (size_t)gtid * 8) = v;
}

// ---------------------------------------------------------------------------
// Fused LSTM step (r7 version — best measured). Grid 256, 512 threads,
// 96 KB dynamic LDS (3 x 32KB A bufs), B direct-to-register from Bpk.
// ---------------------------------------------------------------------------
__global__ __launch_bounds__(512, 2) void lstm_step(
    const __hip_bfloat16* __restrict__ hprev,   // [1024][1024] swizzled
    const __hip_bfloat16* __restrict__ Bpk,     // packed Wh (8 MB)
    const __hip_bfloat16* __restrict__ Epr,     // [V][4096] col=4h+g
    const int* __restrict__ X,
    float* __restrict__ cbuf,                   // [1024][1024] f32
    __hip_bfloat16* __restrict__ hnext,         // swizzled
    __hip_bfloat16* __restrict__ hfin,          // swizzled (last step)
    int t, int last) {
  extern __shared__ __align__(16) char smem[];  // 98304 = 3 x 32KB A bufs
  float* gacc = (float*)smem;                   // [128][132] f32 (aliases)

  const int tid = threadIdx.x;
  const int lane = tid & 63;
  const int w = tid >> 6;
  const int wm = (w >> 1) & 1;
  const int wn = w & 1;
  const int kh = w >> 2;
  const int bid = blockIdx.x;
  const int xcd = bid & 7;
  const int j = bid >> 3;
  const int ht = xcd * 4 + (j & 3);   // Bpk slice pinned to one XCD's L2
  const int mt = j >> 2;
  const int m0 = mt * 128;
  const int h0 = ht * 32;

  const int fr = lane & 15;
  const int kb = (lane >> 4) * 16;
  const int swz = (fr & 7) << 4;
  const int cn = lane & 15;
  const int rb = (lane >> 4) * 4;

  const int crow = tid >> 2;
  const int hq = tid & 3;
  const int prow = m0 + crow;
  const int tok1 = X[prow * SEQ_ + t];

  const __hip_bfloat16* bb =
      Bpk + (size_t)(((ht * 2 + wn) * 2 + kh) * 64) * 512 + lane * 8;

  f32x4 acc[4][4];  // [fm][gate]
#pragma unroll
  for (int i = 0; i < 4; ++i)
#pragma unroll
    for (int g = 0; g < 4; ++g) acc[i][g] = (f32x4)(0.0f);

  auto STAGE_A = [&](int kc, int b) {
#pragma unroll
    for (int q = 0; q < 4; ++q) {
      const int region = q >> 1;           // kh-half
      const int r = (q & 1) * 512 + tid;   // 0..1023 chunks
      const int row = r >> 3, ch = r & 7;
      const __hip_bfloat16* src =
          hprev + (size_t)(m0 + row) * HID_ + region * 512 + kc * 64 + ch * 8;
      async_copy16(smem + b * 32768 + region * 16384 + r * 16, src);
    }
  };

  short8 bR[2][2][4];  // [kc&1][kk][g]

  STAGE_A(0, 0);
#pragma unroll
  for (int kk = 0; kk < 2; ++kk)
#pragma unroll
    for (int g = 0; g < 4; ++g)
      bR[0][kk][g] = *(const short8*)(bb + (0 * 8 + kk * 4 + g) * 512);
  STAGE_A(1, 1);

#pragma unroll
  for (int kc = 0; kc < 8; ++kc) {
    __builtin_amdgcn_s_barrier();
    if (kc + 1 < 8) {
#pragma unroll
      for (int kk = 0; kk < 2; ++kk)
#pragma unroll
        for (int g = 0; g < 4; ++g)
          bR[(kc + 1) & 1][kk][g] =
              *(const short8*)(bb + ((kc + 1) * 8 + kk * 4 + g) * 512);
    }
    if (kc + 2 < 8) STAGE_A(kc + 2, (kc + 2) % 3);
    if (kc < 6)      asm volatile("s_waitcnt vmcnt(24)" ::: "memory");
    else if (kc == 6) asm volatile("s_waitcnt vmcnt(20)" ::: "memory");
    else             asm volatile("s_waitcnt vmcnt(8)" ::: "memory");
    __builtin_amdgcn_sched_barrier(0);

    const char* baseA = smem + (kc % 3) * 32768 + kh * 16384;
    short8 aR[2][4];
#pragma unroll
    for (int kk = 0; kk < 2; ++kk)
#pragma unroll
      for (int f = 0; f < 4; ++f)
        aR[kk][f] = *(const short8*)(baseA + (wm * 64 + f * 16 + fr) * 128 +
                                     ((kk * 64 + kb) ^ swz));
    __builtin_amdgcn_s_setprio(1);
#pragma unroll
    for (int fm = 0; fm < 4; ++fm)
#pragma unroll
      for (int g = 0; g < 4; ++g) {
        mfma_acc(acc[fm][g], aR[0][fm], bR[kc & 1][0][g]);
        mfma_acc(acc[fm][g], aR[1][fm], bR[kc & 1][1][g]);
      }
    __builtin_amdgcn_s_setprio(0);
  }

  ushort4 ep[8];
  float cold[8];
#pragma unroll
  for (int jj = 0; jj < 8; ++jj) {
    ep[jj] = *(const ushort4*)(Epr + (size_t)tok1 * G4_ + (h0 + hq * 8 + jj) * 4);
    cold[jj] = cbuf[(size_t)prow * HID_ + h0 + hq * 8 + jj];
  }

  __syncthreads();
  if (kh == 0) {
#pragma unroll
    for (int fm = 0; fm < 4; ++fm)
#pragma unroll
      for (int g = 0; g < 4; ++g)
#pragma unroll
        for (int r = 0; r < 4; ++r)
          gacc[(wm * 64 + fm * 16 + rb + r) * 132 + (wn * 16 + cn) * 4 + g] =
              acc[fm][g][r];
  }
  __syncthreads();
  if (kh == 1) {
#pragma unroll
    for (int fm = 0; fm < 4; ++fm)
#pragma unroll
      for (int g = 0; g < 4; ++g)
#pragma unroll
        for (int r = 0; r < 4; ++r)
          gacc[(wm * 64 + fm * 16 + rb + r) * 132 + (wn * 16 + cn) * 4 + g] +=
              acc[fm][g][r];
  }
  __syncthreads();

  const float* gr = gacc + crow * 132 + hq * 32;
  f32x4 cnew0, cnew1;
  short8 hv;
#pragma unroll
  for (int jj = 0; jj < 8; ++jj) {
    const f32x4 g4 = *(const f32x4*)(gr + jj * 4);
    const float iv = sigmoidf_(g4[0] + bf2f_(ep[jj].x));
    const float fv = sigmoidf_(g4[1] + bf2f_(ep[jj].y));
    const float gv = tanhf_(g4[2] + bf2f_(ep[jj].z));
    const float ov = sigmoidf_(g4[3] + bf2f_(ep[jj].w));
    const float cv = fv * cold[jj] + iv * gv;
    if (jj < 4) cnew0[jj] = cv; else cnew1[jj - 4] = cv;
    const float hval = ov * tanhf_(cv);
    const __hip_bfloat16 hb = __float2bfloat16(hval);
    hv[jj] = *reinterpret_cast<const short*>(&hb);
  }
  float* cdst = cbuf + (size_t)prow * HID_ + h0 + hq * 8;
  *(f32x4*)cdst = cnew0;
  *(f32x4*)(cdst + 4) = cnew1;
  const int hcolb = h0 + hq * 8;
  const int hswb = (hcolb & ~63) | ((hcolb & 63) ^ ((prow & 7) << 3));
  *(short8*)(hnext + (size_t)prow * HID_ + hswb) = hv;
  if (last) *(short8*)(hfin + (size_t)prow * HID_ + hswb) = hv;
}

// fp32 -> bf16 flat convert; SWZ: k-XOR-swizzle per 64-col group (1024 cols)
template <bool SWZ>
__global__ __launch_bounds__(256) void conv_bf16_k(const float* __restrict__ in,
                                                   __hip_bfloat16* __restrict__ out, int n4) {
  const int i = blockIdx.x * 256 + threadIdx.x;
  if (i >= n4) return;
  const float4 v = ((const float4*)in)[i];
  int o = i * 4;
  if (SWZ) {
    const int row = o >> 10, col = o & 1023;
    const int cs = (col & ~63) | ((col & 63) ^ ((row & 7) << 3));
    o = (o & ~1023) | cs;
  }
  out[o + 0] = __float2bfloat16(v.x);
  out[o + 1] = __float2bfloat16(v.y);
  out[o + 2] = __float2bfloat16(v.z);
  out[o + 3] = __float2bfloat16(v.w);
}

// in[R][C] fp32 -> out[C][R] bf16; PERM: gate-interleave out-rows (4h+g);
// SWZ: XOR-swizzle k per 64-group by out-row&7.
template <bool PERM, bool SWZ>
__global__ __launch_bounds__(256) void transpose_conv(const float* __restrict__ in,
                                                      __hip_bfloat16* __restrict__ out,
                                                      int R, int C) {
  __shared__ float tile[32][33];
  const int c0 = blockIdx.x * 32, r0 = blockIdx.y * 32;
  const int tx = threadIdx.x, ty = threadIdx.y;  // 32x8
#pragma unroll
  for (int i = 0; i < 4; ++i) {
    const int r = r0 + ty + i * 8, cc = c0 + tx;
    tile[ty + i * 8][tx] = (r < R && cc < C) ? in[(size_t)r * C + cc] : 0.f;
  }
  __syncthreads();
#pragma unroll
  for (int i = 0; i < 4; ++i) {
    const int ro = c0 + ty + i * 8, co = r0 + tx;
    if (ro < C && co < R) {
      const int n = PERM ? ((ro & 1023) * 4 + (ro >> 10)) : ro;
      int k = co;
      if (SWZ) k = (k & ~63) | ((k & 63) ^ ((n & 7) << 3));
      out[(size_t)n * R + k] = __float2bfloat16(tile[tx][ty + i * 8]);
    }
  }
}

// bP[4h+g] = bx[g*1024+h] + bh[g*1024+h]
__global__ __launch_bounds__(256) void bias_perm(const float* __restrict__ bx,
                                                 const float* __restrict__ bh,
                                                 float* __restrict__ bP) {
  const int n = blockIdx.x * 256 + threadIdx.x;
  if (n >= G4_) return;
  const int h = n >> 2, g = n & 3;
  bP[n] = bx[g * HID_ + h] + bh[g * HID_ + h];
}

extern "C" void kernel_launch(void* const* d_in, const int* in_sizes, int n_in,
                              void* d_out, int out_size, void* d_ws, size_t ws_size,
                              hipStream_t stream) {
  const int* X = (const int*)d_in[0];
  const float* C = (const float*)d_in[1];
  const float* Wx = (const float*)d_in[2];
  const float* bx = (const float*)d_in[3];
  const float* Wh = (const float*)d_in[4];
  const float* bh = (const float*)d_in[5];
  const float* Wo = (const float*)d_in[6];
  const float* bo = (const float*)d_in[7];
  float* out = (float*)d_out;

  char* p = (char*)d_ws;
  const size_t szCb  = (size_t)NCLS_ * EMB_ * 2;   // Cb, reused for Wot
  const size_t szWxt = (size_t)G4_ * EMB_ * 2;
  const size_t szBpk = (size_t)G4_ * HID_ * 2;     // packed Wh
  const size_t szEpr = (size_t)NCLS_ * G4_ * 2;
  const size_t szH   = (size_t)BATCH_ * HID_ * 2;  // x3: hA, hB, hfin
  const size_t szC   = (size_t)BATCH_ * HID_ * 4;
  const size_t szBp  = (size_t)G4_ * 4;
  if (ws_size < szCb + szWxt + szBpk + szEpr + 3 * szH + szC + szBp) return;

  __hip_bfloat16* Cb   = (__hip_bfloat16*)p; p += szCb;
  __hip_bfloat16* WxtP = (__hip_bfloat16*)p; p += szWxt;
  __hip_bfloat16* Bpk  = (__hip_bfloat16*)p; p += szBpk;
  __hip_bfloat16* Epr  = (__hip_bfloat16*)p; p += szEpr;
  __hip_bfloat16* hA   = (__hip_bfloat16*)p; p += szH;
  __hip_bfloat16* hB   = (__hip_bfloat16*)p; p += szH;
  __hip_bfloat16* hfin = (__hip_bfloat16*)p; p += szH;
  float* cbuf          = (float*)p;          p += szC;
  float* bP            = (float*)p;          p += szBp;

  // 1. C -> bf16, k-swizzled (A operand of E_proj)
  {
    const int n4 = NCLS_ * EMB_ / 4;
    conv_bf16_k<true><<<(n4 + 255) / 256, 256, 0, stream>>>(C, Cb, n4);
  }
  // 2. Wx -> [4096][1024] gate-interleaved rows, k-swizzled (Bt of E_proj)
  transpose_conv<true, true><<<dim3(G4_ / 32, EMB_ / 32), dim3(32, 8), 0, stream>>>(
      Wx, WxtP, EMB_, G4_);
  // 3. Wh -> fragment-packed Bpk (step kernel's B)
  pack_b<<<2048, 256, 0, stream>>>(Wh, Bpk);
  // 4. permuted bias
  bias_perm<<<G4_ / 256, 256, 0, stream>>>(bx, bh, bP);

  // 5. Epr[V][4096] = C @ Wx + (bx+bh)   (grid 16 x 393, 144 KB LDS)
  gemm8p<0><<<dim3(G4_ / 256, (NCLS_ + 127) / 128), 512, 147456, stream>>>(
      Cb, WxtP, nullptr, Epr, NCLS_, G4_, G4_, bP);

  // 6. zero initial state
  hipMemsetAsync(hA, 0, szH, stream);
  hipMemsetAsync(cbuf, 0, szC, stream);

  // 7. 128 fused LSTM steps (r7 config)
  for (int t = 0; t < SEQ_; ++t) {
    const __hip_bfloat16* hp = (t & 1) ? hB : hA;
    __hip_bfloat16* hn = (t & 1) ? hA : hB;
    lstm_step<<<256, 512, 98304, stream>>>(hp, Bpk, Epr, X, cbuf, hn, hfin, t,
                                           (int)(t == SEQ_ - 1));
  }

  // 8. W_out^T, k-swizzled, into Cb region (dead after step 5)
  __hip_bfloat16* Wot = Cb;
  transpose_conv<false, true><<<dim3((NCLS_ + 31) / 32, HID_ / 32), dim3(32, 8), 0,
                                stream>>>(Wo, Wot, HID_, NCLS_);

  // 9. logits = hfin @ W_out + b_out   (grid 197 x 8, 144 KB LDS)
  gemm8p<2><<<dim3((NCLS_ + 255) / 256, BATCH_ / 128), 512, 147456, stream>>>(
      hfin, Wot, out, nullptr, BATCH_, NCLS_, NCLS_, bo);
}